// Round 9
// baseline (267.619 us; speedup 1.0000x reference)
//
#include <hip/hip_runtime.h>
#include <cstdint>
#include <cstddef>

#define N_NODES 50000
#define N_EDGES 1600000
#define TOT_E   (N_EDGES + N_NODES)
#define IN_DIM  256
#define HC      128
#define NHEAD   4
#define OUT_DIM 64

// bucket binning: 32 nodes per bucket, fixed-stride regions
#define BSHIFT  5
#define BNODES  32
#define NBUK    ((N_NODES + BNODES - 1) / BNODES)   // 1563
#define QCAP    1792                                // region cap (mean 1056, +22 sd)
#define CHUNK   16384
#define NCHUNK  ((TOT_E + CHUNK - 1) / CHUNK)       // 101

// k1 MFMA tiling
#define XPAD 264   // bf16 elems per LDS row (256 + 8)
#define HPAD 132   // fp32 elems per LDS row in epilogue (128 + 4)
#define K1_NB ((N_NODES + 63) / 64)                 // 782

typedef __attribute__((ext_vector_type(8))) short bf16x8;
typedef __attribute__((ext_vector_type(4))) float f32x4;

static __device__ __forceinline__ uint16_t f2bf(float f) {
    uint32_t u = __float_as_uint(f);
    uint32_t r = (u + 0x7fffu + ((u >> 16) & 1u)) >> 16;   // RNE
    return (uint16_t)r;
}
static __device__ __forceinline__ float bf_lo(uint32_t u) {
    return __uint_as_float(u << 16);
}
static __device__ __forceinline__ float bf_hi(uint32_t u) {
    return __uint_as_float(u & 0xffff0000u);
}

// ---------------------------------------------------------------------------
// W prep: W fp32 [256][128] -> W^T bf16 [128][256]; also zeroes gcur.
// ---------------------------------------------------------------------------
__global__ __launch_bounds__(256) void w2bf(const float* __restrict__ W,
                                            uint16_t* __restrict__ wt,
                                            int* __restrict__ gcur) {
    int idx = blockIdx.x * 256 + threadIdx.x;   // n*256 + k
    int n = idx >> 8, k = idx & 255;
    wt[idx] = f2bf(W[(size_t)k * HC + n]);
    if (idx < NBUK) gcur[idx] = 0;
}

// ---------------------------------------------------------------------------
// K1P3 (grid-fused): blocks [0, K1_NB) run the MFMA GEMM (h=x@W bf16 +
// fused a_src/a_dst); blocks [K1_NB, K1_NB+NCHUNK) bin edges into
// fixed-stride 32-node-bucket regions (two passes over ei, no reg cache).
// ---------------------------------------------------------------------------
__global__ __launch_bounds__(256) void k1p3(const float* __restrict__ x,
                                            const uint16_t* __restrict__ wt,
                                            const float* __restrict__ att_src,
                                            const float* __restrict__ att_dst,
                                            uint16_t* __restrict__ hb,
                                            float* __restrict__ a_src,
                                            float* __restrict__ a_dst,
                                            const int* __restrict__ ei,
                                            int* __restrict__ gcur,
                                            uint32_t* __restrict__ binned) {
    __shared__ char smem[64 * 528];   // k1: xs/hs; p3: hist[NBUK]+lcur[NBUK] (12.5 KB)
    __shared__ float att_s[HC], att_d[HC];
    const int tid = threadIdx.x;

    if (blockIdx.x < K1_NB) {
        // ---------------- k1: MFMA GEMM ----------------
        uint16_t* xs = (uint16_t*)smem;
        float*    hs = (float*)smem;
        const int wave = tid >> 6;
        const int lane = tid & 63;
        const int m    = lane & 15;
        const int q    = lane >> 4;
        const int row0 = blockIdx.x * 64;

        if (tid < HC) { att_s[tid] = att_src[tid]; att_d[tid] = att_dst[tid]; }

        for (int i = tid * 4; i < 64 * IN_DIM; i += 1024) {
            int r = i >> 8, c = i & 255;
            int gr = row0 + r;
            float4 v = make_float4(0.f, 0.f, 0.f, 0.f);
            if (gr < N_NODES) v = *(const float4*)(x + (size_t)gr * IN_DIM + c);
            uint32_t lo = (uint32_t)f2bf(v.x) | ((uint32_t)f2bf(v.y) << 16);
            uint32_t hi = (uint32_t)f2bf(v.z) | ((uint32_t)f2bf(v.w) << 16);
            *(uint2*)(xs + r * XPAD + c) = make_uint2(lo, hi);
        }
        __syncthreads();

        f32x4 acc[8];
        #pragma unroll
        for (int t = 0; t < 8; ++t) acc[t] = (f32x4){0.f, 0.f, 0.f, 0.f};

        const int arow = wave * 16 + m;
        #pragma unroll
        for (int ks = 0; ks < IN_DIM; ks += 32) {
            bf16x8 a = *(const bf16x8*)(xs + arow * XPAD + ks + q * 8);
            #pragma unroll
            for (int t = 0; t < 8; ++t) {
                bf16x8 b = *(const bf16x8*)(wt + (size_t)(t * 16 + m) * IN_DIM + ks + q * 8);
                acc[t] = __builtin_amdgcn_mfma_f32_16x16x32_bf16(a, b, acc[t], 0, 0, 0);
            }
        }
        __syncthreads();

        // C/D: col = lane&15, row = (lane>>4)*4 + reg
        #pragma unroll
        for (int t = 0; t < 8; ++t)
            #pragma unroll
            for (int r = 0; r < 4; ++r)
                hs[(wave * 16 + q * 4 + r) * HPAD + t * 16 + m] = acc[t][r];
        __syncthreads();

        for (int i = tid * 4; i < 64 * HC; i += 1024) {
            int r = i >> 7, c = i & 127;
            if (row0 + r < N_NODES) {
                float4 v = *(const float4*)(hs + r * HPAD + c);
                uint32_t lo = (uint32_t)f2bf(v.x) | ((uint32_t)f2bf(v.y) << 16);
                uint32_t hi = (uint32_t)f2bf(v.z) | ((uint32_t)f2bf(v.w) << 16);
                *(uint2*)(hb + (size_t)(row0 + r) * HC + c) = make_uint2(lo, hi);
            }
        }
        {
            int r = tid >> 2, hd = tid & 3;
            if (row0 + r < N_NODES) {
                float s = 0.f, d = 0.f;
                #pragma unroll
                for (int j = 0; j < 32; ++j) {
                    float v = hs[r * HPAD + hd * 32 + j];
                    s = fmaf(v, att_s[hd * 32 + j], s);
                    d = fmaf(v, att_d[hd * 32 + j], d);
                }
                a_src[(row0 + r) * NHEAD + hd] = s;
                a_dst[(row0 + r) * NHEAD + hd] = d;
            }
        }
    } else {
        // ---------------- p3: two-pass bin into 32-node-bucket regions ------
        int* hist = (int*)smem;
        int* lcur = hist + NBUK;
        for (int i = tid; i < NBUK; i += 256) hist[i] = 0;
        __syncthreads();

        const int e0 = (blockIdx.x - K1_NB) * CHUNK;
        int e1 = e0 + CHUNK; if (e1 > TOT_E) e1 = TOT_E;

        for (int e = e0 + tid; e < e1; e += 256) {
            int dst = (e < N_EDGES) ? ei[N_EDGES + e] : (e - N_EDGES);
            atomicAdd(&hist[dst >> BSHIFT], 1);
        }
        __syncthreads();
        for (int i = tid; i < NBUK; i += 256) {
            int c = hist[i];
            lcur[i] = c ? atomicAdd(&gcur[i], c) : 0;   // within-region base
        }
        __syncthreads();
        for (int e = e0 + tid; e < e1; e += 256) {
            int src, dst;
            if (e < N_EDGES) { src = ei[e]; dst = ei[N_EDGES + e]; }
            else             { src = e - N_EDGES; dst = src; }
            int b = dst >> BSHIFT;
            int pos = atomicAdd(&lcur[b], 1);
            if (pos < QCAP)
                binned[(size_t)b * QCAP + pos] =
                    (uint32_t)src | ((uint32_t)(dst & (BNODES - 1)) << 16);
        }
    }
}

// ---------------------------------------------------------------------------
// Q4 (fused group+aggregate): one 512-thr block per 32-node bucket. Stage the
// bucket's own region (no filtering, no re-read), per-wave sub-histograms,
// 32-lane scan, regroup to per-node lists (uint16 srcs), then 8 waves x
// 4 nodes of the R7-winning gather loop. Output act bf16.
// ---------------------------------------------------------------------------
__global__ __launch_bounds__(512) void q4_agg(const uint32_t* __restrict__ binned,
                                              const int* __restrict__ gcur,
                                              const uint32_t* __restrict__ hb32,
                                              const float* __restrict__ a_src,
                                              const float* __restrict__ a_dst,
                                              const float* __restrict__ bias,
                                              uint32_t* __restrict__ actb) {
    __shared__ uint32_t ew[QCAP];       // 7 KB raw words
    __shared__ uint16_t ew2[QCAP];      // 3.5 KB grouped srcs
    __shared__ int ncnt[8][32];         // per-wave sub-histograms
    __shared__ int nbeg[32], ncur[32], ntot[32];
    const int b   = blockIdx.x;
    const int tid = threadIdx.x;
    const int wv  = tid >> 6;

    int cnt = gcur[b];
    if (cnt > QCAP) cnt = QCAP;

    if (tid < 256) { ((int*)ncnt)[tid] = 0; }
    __syncthreads();

    const uint32_t* bb = binned + (size_t)b * QCAP;
    for (int i = tid; i < cnt; i += 512) {
        uint32_t w = bb[i];
        ew[i] = w;
        atomicAdd(&ncnt[wv][(w >> 16) & 31], 1);
    }
    __syncthreads();

    if (tid < 32) {
        int v = 0;
        #pragma unroll
        for (int w = 0; w < 8; ++w) v += ncnt[w][tid];
        int inc = v;
        #pragma unroll
        for (int d = 1; d < 32; d <<= 1) {
            int t = __shfl_up(inc, d, 64);
            if (tid >= d) inc += t;
        }
        nbeg[tid] = inc - v;
        ncur[tid] = inc - v;
        ntot[tid] = v;
    }
    __syncthreads();
    for (int i = tid; i < cnt; i += 512) {
        uint32_t w = ew[i];
        int ln  = (w >> 16) & 31;
        int pos = atomicAdd(&ncur[ln], 1);
        ew2[pos] = (uint16_t)w;
    }
    __syncthreads();

    // gather: wave wv handles local nodes wv*4 .. wv*4+3
    const int lane = tid & 63;
    const int head = lane >> 4;
    const uint32_t* hbl = hb32 + lane;
    const float*    ash = a_src + head;

    for (int k = 0; k < 4; ++k) {
        const int ln   = wv * 4 + k;
        const int node = b * BNODES + ln;
        if (node >= N_NODES) continue;

        const float ad = a_dst[node * NHEAD + head];
        int p = nbeg[ln];
        const int end = p + ntot[ln];

        float l = 0.f, acc0 = 0.f, acc1 = 0.f;

        for (; p + 4 <= end; p += 4) {
            int s0 = (int)ew2[p + 0];
            int s1 = (int)ew2[p + 1];
            int s2 = (int)ew2[p + 2];
            int s3 = (int)ew2[p + 3];
            float e0 = ash[s0 * NHEAD] + ad;
            float e1 = ash[s1 * NHEAD] + ad;
            float e2 = ash[s2 * NHEAD] + ad;
            float e3 = ash[s3 * NHEAD] + ad;
            uint32_t u0 = hbl[(size_t)s0 * 64];
            uint32_t u1 = hbl[(size_t)s1 * 64];
            uint32_t u2 = hbl[(size_t)s2 * 64];
            uint32_t u3 = hbl[(size_t)s3 * 64];
            e0 = fmaxf(e0, 0.2f * e0);
            e1 = fmaxf(e1, 0.2f * e1);
            e2 = fmaxf(e2, 0.2f * e2);
            e3 = fmaxf(e3, 0.2f * e3);
            float w0 = __expf(e0), w1 = __expf(e1);
            float w2 = __expf(e2), w3 = __expf(e3);
            l += (w0 + w1) + (w2 + w3);
            acc0 = fmaf(w0, bf_lo(u0), acc0);
            acc1 = fmaf(w0, bf_hi(u0), acc1);
            acc0 = fmaf(w1, bf_lo(u1), acc0);
            acc1 = fmaf(w1, bf_hi(u1), acc1);
            acc0 = fmaf(w2, bf_lo(u2), acc0);
            acc1 = fmaf(w2, bf_hi(u2), acc1);
            acc0 = fmaf(w3, bf_lo(u3), acc0);
            acc1 = fmaf(w3, bf_hi(u3), acc1);
        }
        for (; p < end; ++p) {
            int s = (int)ew2[p];
            float e = ash[s * NHEAD] + ad;
            e = fmaxf(e, 0.2f * e);
            float w = __expf(e);
            uint32_t u = hbl[(size_t)s * 64];
            l += w;
            acc0 = fmaf(w, bf_lo(u), acc0);
            acc1 = fmaf(w, bf_hi(u), acc1);
        }

        const int c0 = lane << 1;
        float inv = 1.f / l;              // self loop => l > 0
        float o0 = acc0 * inv + bias[c0];
        float o1 = acc1 * inv + bias[c0 + 1];
        o0 = (o0 > 0.f) ? o0 : (__expf(o0) - 1.f);
        o1 = (o1 > 0.f) ? o1 : (__expf(o1) - 1.f);
        actb[(size_t)node * 64 + lane] = (uint32_t)f2bf(o0) | ((uint32_t)f2bf(o1) << 16);
    }
}

// ---------------------------------------------------------------------------
// K7: out = act @ lin_W + lin_b   [N,128] @ [128,64]; act read as bf16
// ---------------------------------------------------------------------------
__global__ __launch_bounds__(512) void k7_out(const uint32_t* __restrict__ actb,
                                              const float* __restrict__ linW,
                                              const float* __restrict__ linb,
                                              float* __restrict__ out) {
    __shared__ float sW[HC * OUT_DIM];   // 32 KB
    __shared__ float srow[32 * HC];      // 16 KB
    const int tid   = threadIdx.x;
    const int node0 = blockIdx.x * 32;

    for (int i = tid * 4; i < HC * OUT_DIM; i += 512 * 4)
        *(float4*)(sW + i) = *(const float4*)(linW + i);
    {
        int i = tid * 4;                 // word index: 32 rows x 64 words
        int r = i >> 6, cw = i & 63;
        int node = node0 + r;
        uint4 v = make_uint4(0, 0, 0, 0);
        if (node < N_NODES) v = *(const uint4*)(actb + (size_t)node * 64 + cw);
        float* d = srow + r * HC + cw * 2;
        d[0] = bf_lo(v.x); d[1] = bf_hi(v.x);
        d[2] = bf_lo(v.y); d[3] = bf_hi(v.y);
        d[4] = bf_lo(v.z); d[5] = bf_hi(v.z);
        d[6] = bf_lo(v.w); d[7] = bf_hi(v.w);
    }
    __syncthreads();

    const int r    = tid >> 4;
    const int colb = (tid & 15) << 2;
    float4 acc = *(const float4*)(linb + colb);
    const float* rp = srow + r * HC;

    #pragma unroll
    for (int k = 0; k < HC; k += 4) {
        float4 xv = *(const float4*)(rp + k);
        float4 w0 = *(const float4*)(sW + (k + 0) * OUT_DIM + colb);
        float4 w1 = *(const float4*)(sW + (k + 1) * OUT_DIM + colb);
        float4 w2 = *(const float4*)(sW + (k + 2) * OUT_DIM + colb);
        float4 w3 = *(const float4*)(sW + (k + 3) * OUT_DIM + colb);
        acc.x += xv.x * w0.x; acc.x += xv.y * w1.x; acc.x += xv.z * w2.x; acc.x += xv.w * w3.x;
        acc.y += xv.x * w0.y; acc.y += xv.y * w1.y; acc.y += xv.z * w2.y; acc.y += xv.w * w3.y;
        acc.z += xv.x * w0.z; acc.z += xv.y * w1.z; acc.z += xv.z * w2.z; acc.z += xv.w * w3.z;
        acc.w += xv.x * w0.w; acc.w += xv.y * w1.w; acc.w += xv.z * w2.w; acc.w += xv.w * w3.w;
    }

    int node = node0 + r;
    if (node < N_NODES)
        *(float4*)(out + (size_t)node * OUT_DIM + colb) = acc;
}

// ---------------------------------------------------------------------------
extern "C" void kernel_launch(void* const* d_in, const int* in_sizes, int n_in,
                              void* d_out, int out_size, void* d_ws, size_t ws_size,
                              hipStream_t stream) {
    (void)in_sizes; (void)n_in; (void)out_size; (void)ws_size;
    const float* x       = (const float*)d_in[0];
    const int*   ei      = (const int*)d_in[1];
    const float* W       = (const float*)d_in[2];
    const float* att_src = (const float*)d_in[3];
    const float* att_dst = (const float*)d_in[4];
    const float* bias    = (const float*)d_in[5];
    const float* linW    = (const float*)d_in[6];
    const float* linb    = (const float*)d_in[7];
    float*       out     = (float*)d_out;

    char*  ws  = (char*)d_ws;
    size_t off = 0;
    auto alloc = [&](size_t bytes) -> void* {
        void* p = ws + off;
        off += (bytes + 255) & ~(size_t)255;
        return p;
    };
    uint16_t* hb     = (uint16_t*)alloc((size_t)N_NODES * HC * 2);
    uint16_t* wt     = (uint16_t*)alloc((size_t)HC * IN_DIM * 2);
    uint32_t* actb   = (uint32_t*)alloc((size_t)N_NODES * 64 * 4);
    float*    a_src  = (float*)alloc((size_t)N_NODES * NHEAD * 4);
    float*    a_dst  = (float*)alloc((size_t)N_NODES * NHEAD * 4);
    int*      gcur   = (int*)alloc((size_t)NBUK * 4);
    uint32_t* binned = (uint32_t*)alloc((size_t)NBUK * QCAP * 4);

    w2bf<<<(HC * IN_DIM) / 256, 256, 0, stream>>>(W, wt, gcur);
    k1p3<<<K1_NB + NCHUNK, 256, 0, stream>>>(x, wt, att_src, att_dst,
                                             hb, a_src, a_dst,
                                             ei, gcur, binned);
    q4_agg<<<NBUK, 512, 0, stream>>>(binned, gcur, (const uint32_t*)hb,
                                     a_src, a_dst, bias, actb);
    k7_out<<<(N_NODES + 31) / 32, 512, 0, stream>>>(actb, linW, linb, out);
}

// Round 10
// 248.108 us; speedup vs baseline: 1.0786x; 1.0786x over previous
//
#include <hip/hip_runtime.h>
#include <cstdint>
#include <cstddef>

#define N_NODES 50000
#define N_EDGES 1600000
#define TOT_E   (N_EDGES + N_NODES)
#define IN_DIM  256
#define HC      128
#define NHEAD   4
#define OUT_DIM 64

// p3 binning: 128-node buckets (few fat buckets -> long write runs, few
// global atomics). q4 consumes at 32-node granularity via filtered reads.
#define SHIFT   7
#define BSZ     128
#define NBUK    ((N_NODES + BSZ - 1) / BSZ)      // 391
#define CHUNK   2048
#define EPT     8                                // CHUNK / 256
#define NCHUNK  ((TOT_E + CHUNK - 1) / CHUNK)    // 806
#define CAP     6144                             // bucket cap (mean 4220, +29 sd)
#define QCAP    2048                             // 32-node group cap (mean 1056, +30 sd)

// k1 MFMA tiling
#define XPAD 264   // bf16 elems per LDS row (256 + 8)
#define HPAD 132   // fp32 elems per LDS row in epilogue (128 + 4)
#define K1_NB ((N_NODES + 63) / 64)              // 782

typedef __attribute__((ext_vector_type(8))) short bf16x8;
typedef __attribute__((ext_vector_type(4))) float f32x4;

static __device__ __forceinline__ uint16_t f2bf(float f) {
    uint32_t u = __float_as_uint(f);
    uint32_t r = (u + 0x7fffu + ((u >> 16) & 1u)) >> 16;   // RNE
    return (uint16_t)r;
}
static __device__ __forceinline__ float bf_lo(uint32_t u) {
    return __uint_as_float(u << 16);
}
static __device__ __forceinline__ float bf_hi(uint32_t u) {
    return __uint_as_float(u & 0xffff0000u);
}

// ---------------------------------------------------------------------------
// W prep: W fp32 [256][128] -> W^T bf16 [128][256]; also zeroes gcur.
// ---------------------------------------------------------------------------
__global__ __launch_bounds__(256) void w2bf(const float* __restrict__ W,
                                            uint16_t* __restrict__ wt,
                                            int* __restrict__ gcur) {
    int idx = blockIdx.x * 256 + threadIdx.x;   // n*256 + k
    int n = idx >> 8, k = idx & 255;
    wt[idx] = f2bf(W[(size_t)k * HC + n]);
    if (idx < NBUK) gcur[idx] = 0;
}

// ---------------------------------------------------------------------------
// K1P3 (grid-fused): blocks [0, K1_NB) run the MFMA GEMM (h=x@W bf16 +
// fused a_src/a_dst); blocks [K1_NB, K1_NB+NCHUNK) bin edges into
// fixed-stride 128-node-bucket regions (R8-proven config: wreg cache,
// 806 blocks, ~5-word write runs, 315K global atomics).
// ---------------------------------------------------------------------------
__global__ __launch_bounds__(256) void k1p3(const float* __restrict__ x,
                                            const uint16_t* __restrict__ wt,
                                            const float* __restrict__ att_src,
                                            const float* __restrict__ att_dst,
                                            uint16_t* __restrict__ hb,
                                            float* __restrict__ a_src,
                                            float* __restrict__ a_dst,
                                            const int* __restrict__ ei,
                                            int* __restrict__ gcur,
                                            uint32_t* __restrict__ binned) {
    __shared__ char smem[64 * 528];   // k1: xs/hs; p3: hist[NBUK]+lcur[NBUK]
    __shared__ float att_s[HC], att_d[HC];
    const int tid = threadIdx.x;

    if (blockIdx.x < K1_NB) {
        // ---------------- k1: MFMA GEMM ----------------
        uint16_t* xs = (uint16_t*)smem;
        float*    hs = (float*)smem;
        const int wave = tid >> 6;
        const int lane = tid & 63;
        const int m    = lane & 15;
        const int q    = lane >> 4;
        const int row0 = blockIdx.x * 64;

        if (tid < HC) { att_s[tid] = att_src[tid]; att_d[tid] = att_dst[tid]; }

        for (int i = tid * 4; i < 64 * IN_DIM; i += 1024) {
            int r = i >> 8, c = i & 255;
            int gr = row0 + r;
            float4 v = make_float4(0.f, 0.f, 0.f, 0.f);
            if (gr < N_NODES) v = *(const float4*)(x + (size_t)gr * IN_DIM + c);
            uint32_t lo = (uint32_t)f2bf(v.x) | ((uint32_t)f2bf(v.y) << 16);
            uint32_t hi = (uint32_t)f2bf(v.z) | ((uint32_t)f2bf(v.w) << 16);
            *(uint2*)(xs + r * XPAD + c) = make_uint2(lo, hi);
        }
        __syncthreads();

        f32x4 acc[8];
        #pragma unroll
        for (int t = 0; t < 8; ++t) acc[t] = (f32x4){0.f, 0.f, 0.f, 0.f};

        const int arow = wave * 16 + m;
        #pragma unroll
        for (int ks = 0; ks < IN_DIM; ks += 32) {
            bf16x8 a = *(const bf16x8*)(xs + arow * XPAD + ks + q * 8);
            #pragma unroll
            for (int t = 0; t < 8; ++t) {
                bf16x8 b = *(const bf16x8*)(wt + (size_t)(t * 16 + m) * IN_DIM + ks + q * 8);
                acc[t] = __builtin_amdgcn_mfma_f32_16x16x32_bf16(a, b, acc[t], 0, 0, 0);
            }
        }
        __syncthreads();

        // C/D: col = lane&15, row = (lane>>4)*4 + reg
        #pragma unroll
        for (int t = 0; t < 8; ++t)
            #pragma unroll
            for (int r = 0; r < 4; ++r)
                hs[(wave * 16 + q * 4 + r) * HPAD + t * 16 + m] = acc[t][r];
        __syncthreads();

        for (int i = tid * 4; i < 64 * HC; i += 1024) {
            int r = i >> 7, c = i & 127;
            if (row0 + r < N_NODES) {
                float4 v = *(const float4*)(hs + r * HPAD + c);
                uint32_t lo = (uint32_t)f2bf(v.x) | ((uint32_t)f2bf(v.y) << 16);
                uint32_t hi = (uint32_t)f2bf(v.z) | ((uint32_t)f2bf(v.w) << 16);
                *(uint2*)(hb + (size_t)(row0 + r) * HC + c) = make_uint2(lo, hi);
            }
        }
        {
            int r = tid >> 2, hd = tid & 3;
            if (row0 + r < N_NODES) {
                float s = 0.f, d = 0.f;
                #pragma unroll
                for (int j = 0; j < 32; ++j) {
                    float v = hs[r * HPAD + hd * 32 + j];
                    s = fmaf(v, att_s[hd * 32 + j], s);
                    d = fmaf(v, att_d[hd * 32 + j], d);
                }
                a_src[(row0 + r) * NHEAD + hd] = s;
                a_dst[(row0 + r) * NHEAD + hd] = d;
            }
        }
    } else {
        // ---------------- p3: bin edges (R8 config) ----
        int* hist = (int*)smem;
        int* lcur = hist + NBUK;
        for (int i = tid; i < NBUK; i += 256) hist[i] = 0;
        __syncthreads();

        uint32_t wreg[EPT];
        const int base = (blockIdx.x - K1_NB) * CHUNK;
        #pragma unroll
        for (int k = 0; k < EPT; ++k) {
            int e = base + k * 256 + tid;
            uint32_t word = 0xFFFFFFFFu;
            if (e < TOT_E) {
                int src, dst;
                if (e < N_EDGES) { src = ei[e]; dst = ei[N_EDGES + e]; }
                else             { src = e - N_EDGES; dst = src; }
                int b = dst >> SHIFT;
                word = (uint32_t)src | ((uint32_t)(dst & (BSZ - 1)) << 16)
                     | ((uint32_t)b << 23);
                atomicAdd(&hist[b], 1);
            }
            wreg[k] = word;
        }
        __syncthreads();
        for (int i = tid; i < NBUK; i += 256) {
            int c = hist[i];
            lcur[i] = c ? atomicAdd(&gcur[i], c) : 0;   // within-bucket base
        }
        __syncthreads();
        #pragma unroll
        for (int k = 0; k < EPT; ++k) {
            uint32_t word = wreg[k];
            if (word != 0xFFFFFFFFu) {
                int b = (int)(word >> 23);
                int pos = atomicAdd(&lcur[b], 1);
                if (pos < CAP) binned[(size_t)b * CAP + pos] = word;
            }
        }
    }
}

// ---------------------------------------------------------------------------
// Q4: block (b,sub) aggregates 32 nodes of 128-bucket b. Two filtered passes
// directly over the bucket's global region (L2-hot, no LDS staging, no
// append counter): pass1 histogram ncnt[32], scan, pass2 regroup srcs into
// ew2 (uint16, 4 KB). Then 4 waves x 8 nodes of the R7-winning gather loop.
// ---------------------------------------------------------------------------
__global__ __launch_bounds__(256) void q4_agg(const uint32_t* __restrict__ binned,
                                              const int* __restrict__ gcur,
                                              const uint32_t* __restrict__ hb32,
                                              const float* __restrict__ a_src,
                                              const float* __restrict__ a_dst,
                                              const float* __restrict__ bias,
                                              uint32_t* __restrict__ actb) {
    __shared__ uint16_t ew2[QCAP];      // 4 KB grouped srcs
    __shared__ int ncnt[32], nbeg[32], ncur[32];
    const int b   = blockIdx.x >> 2;
    const int sub = blockIdx.x & 3;
    const int tid = threadIdx.x;

    int cnt = gcur[b];
    if (cnt > CAP) cnt = CAP;

    if (tid < 32) ncnt[tid] = 0;
    __syncthreads();

    const uint32_t* bb = binned + (size_t)b * CAP;
    for (int i = tid; i < cnt; i += 256) {
        uint32_t w = bb[i];
        if (((w >> 21) & 3) == (uint32_t)sub)
            atomicAdd(&ncnt[(w >> 16) & 31], 1);
    }
    __syncthreads();

    if (tid < 32) {                       // inclusive scan of 32 counts
        int v = ncnt[tid];
        int inc = v;
        #pragma unroll
        for (int d = 1; d < 32; d <<= 1) {
            int t = __shfl_up(inc, d, 64);
            if (tid >= d) inc += t;
        }
        nbeg[tid] = inc - v;
        ncur[tid] = inc - v;
    }
    __syncthreads();
    for (int i = tid; i < cnt; i += 256) {
        uint32_t w = bb[i];
        if (((w >> 21) & 3) == (uint32_t)sub) {
            int pos = atomicAdd(&ncur[(w >> 16) & 31], 1);
            if (pos < QCAP) ew2[pos] = (uint16_t)w;
        }
    }
    __syncthreads();

    // gather: wave wv handles local nodes wv*8 .. wv*8+7
    const int wv   = tid >> 6;
    const int lane = tid & 63;
    const int head = lane >> 4;
    const uint32_t* hbl = hb32 + lane;
    const float*    ash = a_src + head;

    for (int k = 0; k < 8; ++k) {
        const int ln   = wv * 8 + k;
        const int node = b * BSZ + sub * 32 + ln;
        if (node >= N_NODES) continue;

        const float ad = a_dst[node * NHEAD + head];
        int p = nbeg[ln];
        const int end = p + ncnt[ln];

        float l = 0.f, acc0 = 0.f, acc1 = 0.f;

        for (; p + 4 <= end; p += 4) {
            int s0 = (int)ew2[p + 0];
            int s1 = (int)ew2[p + 1];
            int s2 = (int)ew2[p + 2];
            int s3 = (int)ew2[p + 3];
            float e0 = ash[s0 * NHEAD] + ad;
            float e1 = ash[s1 * NHEAD] + ad;
            float e2 = ash[s2 * NHEAD] + ad;
            float e3 = ash[s3 * NHEAD] + ad;
            uint32_t u0 = hbl[(size_t)s0 * 64];
            uint32_t u1 = hbl[(size_t)s1 * 64];
            uint32_t u2 = hbl[(size_t)s2 * 64];
            uint32_t u3 = hbl[(size_t)s3 * 64];
            e0 = fmaxf(e0, 0.2f * e0);
            e1 = fmaxf(e1, 0.2f * e1);
            e2 = fmaxf(e2, 0.2f * e2);
            e3 = fmaxf(e3, 0.2f * e3);
            float w0 = __expf(e0), w1 = __expf(e1);
            float w2 = __expf(e2), w3 = __expf(e3);
            l += (w0 + w1) + (w2 + w3);
            acc0 = fmaf(w0, bf_lo(u0), acc0);
            acc1 = fmaf(w0, bf_hi(u0), acc1);
            acc0 = fmaf(w1, bf_lo(u1), acc0);
            acc1 = fmaf(w1, bf_hi(u1), acc1);
            acc0 = fmaf(w2, bf_lo(u2), acc0);
            acc1 = fmaf(w2, bf_hi(u2), acc1);
            acc0 = fmaf(w3, bf_lo(u3), acc0);
            acc1 = fmaf(w3, bf_hi(u3), acc1);
        }
        for (; p < end; ++p) {
            int s = (int)ew2[p];
            float e = ash[s * NHEAD] + ad;
            e = fmaxf(e, 0.2f * e);
            float w = __expf(e);
            uint32_t u = hbl[(size_t)s * 64];
            l += w;
            acc0 = fmaf(w, bf_lo(u), acc0);
            acc1 = fmaf(w, bf_hi(u), acc1);
        }

        const int c0 = lane << 1;
        float inv = 1.f / l;              // self loop => l > 0
        float o0 = acc0 * inv + bias[c0];
        float o1 = acc1 * inv + bias[c0 + 1];
        o0 = (o0 > 0.f) ? o0 : (__expf(o0) - 1.f);
        o1 = (o1 > 0.f) ? o1 : (__expf(o1) - 1.f);
        actb[(size_t)node * 64 + lane] = (uint32_t)f2bf(o0) | ((uint32_t)f2bf(o1) << 16);
    }
}

// ---------------------------------------------------------------------------
// K7: out = act @ lin_W + lin_b   [N,128] @ [128,64]; act read as bf16
// ---------------------------------------------------------------------------
__global__ __launch_bounds__(512) void k7_out(const uint32_t* __restrict__ actb,
                                              const float* __restrict__ linW,
                                              const float* __restrict__ linb,
                                              float* __restrict__ out) {
    __shared__ float sW[HC * OUT_DIM];   // 32 KB
    __shared__ float srow[32 * HC];      // 16 KB
    const int tid   = threadIdx.x;
    const int node0 = blockIdx.x * 32;

    for (int i = tid * 4; i < HC * OUT_DIM; i += 512 * 4)
        *(float4*)(sW + i) = *(const float4*)(linW + i);
    {
        int i = tid * 4;                 // word index: 32 rows x 64 words
        int r = i >> 6, cw = i & 63;
        int node = node0 + r;
        uint4 v = make_uint4(0, 0, 0, 0);
        if (node < N_NODES) v = *(const uint4*)(actb + (size_t)node * 64 + cw);
        float* d = srow + r * HC + cw * 2;
        d[0] = bf_lo(v.x); d[1] = bf_hi(v.x);
        d[2] = bf_lo(v.y); d[3] = bf_hi(v.y);
        d[4] = bf_lo(v.z); d[5] = bf_hi(v.z);
        d[6] = bf_lo(v.w); d[7] = bf_hi(v.w);
    }
    __syncthreads();

    const int r    = tid >> 4;
    const int colb = (tid & 15) << 2;
    float4 acc = *(const float4*)(linb + colb);
    const float* rp = srow + r * HC;

    #pragma unroll
    for (int k = 0; k < HC; k += 4) {
        float4 xv = *(const float4*)(rp + k);
        float4 w0 = *(const float4*)(sW + (k + 0) * OUT_DIM + colb);
        float4 w1 = *(const float4*)(sW + (k + 1) * OUT_DIM + colb);
        float4 w2 = *(const float4*)(sW + (k + 2) * OUT_DIM + colb);
        float4 w3 = *(const float4*)(sW + (k + 3) * OUT_DIM + colb);
        acc.x += xv.x * w0.x; acc.x += xv.y * w1.x; acc.x += xv.z * w2.x; acc.x += xv.w * w3.x;
        acc.y += xv.x * w0.y; acc.y += xv.y * w1.y; acc.y += xv.z * w2.y; acc.y += xv.w * w3.y;
        acc.z += xv.x * w0.z; acc.z += xv.y * w1.z; acc.z += xv.z * w2.z; acc.z += xv.w * w3.z;
        acc.w += xv.x * w0.w; acc.w += xv.y * w1.w; acc.w += xv.z * w2.w; acc.w += xv.w * w3.w;
    }

    int node = node0 + r;
    if (node < N_NODES)
        *(float4*)(out + (size_t)node * OUT_DIM + colb) = acc;
}

// ---------------------------------------------------------------------------
extern "C" void kernel_launch(void* const* d_in, const int* in_sizes, int n_in,
                              void* d_out, int out_size, void* d_ws, size_t ws_size,
                              hipStream_t stream) {
    (void)in_sizes; (void)n_in; (void)out_size; (void)ws_size;
    const float* x       = (const float*)d_in[0];
    const int*   ei      = (const int*)d_in[1];
    const float* W       = (const float*)d_in[2];
    const float* att_src = (const float*)d_in[3];
    const float* att_dst = (const float*)d_in[4];
    const float* bias    = (const float*)d_in[5];
    const float* linW    = (const float*)d_in[6];
    const float* linb    = (const float*)d_in[7];
    float*       out     = (float*)d_out;

    char*  ws  = (char*)d_ws;
    size_t off = 0;
    auto alloc = [&](size_t bytes) -> void* {
        void* p = ws + off;
        off += (bytes + 255) & ~(size_t)255;
        return p;
    };
    uint16_t* hb     = (uint16_t*)alloc((size_t)N_NODES * HC * 2);
    uint16_t* wt     = (uint16_t*)alloc((size_t)HC * IN_DIM * 2);
    uint32_t* actb   = (uint32_t*)alloc((size_t)N_NODES * 64 * 4);
    float*    a_src  = (float*)alloc((size_t)N_NODES * NHEAD * 4);
    float*    a_dst  = (float*)alloc((size_t)N_NODES * NHEAD * 4);
    int*      gcur   = (int*)alloc((size_t)NBUK * 4);
    uint32_t* binned = (uint32_t*)alloc((size_t)NBUK * CAP * 4);

    w2bf<<<(HC * IN_DIM) / 256, 256, 0, stream>>>(W, wt, gcur);
    k1p3<<<K1_NB + NCHUNK, 256, 0, stream>>>(x, wt, att_src, att_dst,
                                             hb, a_src, a_dst,
                                             ei, gcur, binned);
    q4_agg<<<NBUK * 4, 256, 0, stream>>>(binned, gcur, (const uint32_t*)hb,
                                         a_src, a_dst, bias, actb);
    k7_out<<<(N_NODES + 31) / 32, 512, 0, stream>>>(actb, linW, linb, out);
}